// Round 3
// baseline (627.971 us; speedup 1.0000x reference)
//
#include <hip/hip_runtime.h>

#define NB 2048      // query positions
#define NOBS 2048    // observed positions
#define NP 15        // poly features
#define NG 21        // graph features
#define NE 64        // graph dict columns
#define ND 256       // opd dim
#define NK 36        // NP + NG
#define NDD (ND*ND)  // 65536
#define RB 16        // rows (b) per tile in expansion
#define CT 2         // columns (j) per thread in expansion
#define TILES 8      // row tiles per block (S stays register-resident)
#define QB 8         // queries per block in knn

typedef float vfloat4 __attribute__((ext_vector_type(4)));
typedef float vfloat2 __attribute__((ext_vector_type(2)));

// ---------------------------------------------------------------------------
// Kernel 1: batched 1-NN + coefficient build (unchanged from prev round).
// grid = NB/QB = 256 blocks x 256 threads. obs_pos + alphas staged once per
// block; one query per 32-lane half-wave; packed (d2,idx) shfl_xor reduce.
// Output TRANSPOSED: coeffT[k][b].
// ---------------------------------------------------------------------------
__global__ __launch_bounds__(256) void knn_coeff_kernel(
    const float* __restrict__ positions,   // [NB][2]
    const float* __restrict__ obs_pos,     // [NOBS][2]
    const float* __restrict__ poly_dic,    // [NOBS][NP]
    const float* __restrict__ graph_dic,   // [NOBS][NE]
    const float* __restrict__ alpha_poly,  // [NP][NP]
    const float* __restrict__ alpha_graph, // [NE][NG]
    float* __restrict__ coeffT)            // [NK][NB]  (transposed!)
{
    __shared__ float2 sobs[NOBS];      // 16 KB
    __shared__ float  sap[NP*NP];      // 0.9 KB
    __shared__ float  sag[NE*NG];      // 5.25 KB
    __shared__ int    sbest[QB];

    const int tid = threadIdx.x;

    const float2* obs2 = (const float2*)obs_pos;
    for (int i = tid; i < NOBS; i += 256) sobs[i] = obs2[i];
    for (int i = tid; i < NP*NP; i += 256) sap[i] = alpha_poly[i];
    for (int i = tid; i < NE*NG; i += 256) sag[i] = alpha_graph[i];
    __syncthreads();

    const int w    = tid >> 6;      // wave 0..3
    const int lane = tid & 63;
    const int half = lane >> 5;     // 0/1: which query of this wave
    const int l32  = lane & 31;
    const int q    = blockIdx.x * QB + 2*w + half;

    const float qx = positions[2*q + 0];
    const float qy = positions[2*q + 1];

    unsigned long long best = ~0ull;
    #pragma unroll 8
    for (int it = 0; it < NOBS/32; ++it) {
        const int i = l32 + it*32;
        const float dx = qx - sobs[i].x;
        const float dy = qy - sobs[i].y;
        const float d2 = dx*dx + dy*dy;
        const unsigned long long key =
            ((unsigned long long)__float_as_uint(d2) << 32) | (unsigned)i;
        if (key < best) best = key;
    }
    #pragma unroll
    for (int m = 16; m > 0; m >>= 1) {
        const unsigned long long o = __shfl_xor(best, m, 32);
        if (o < best) best = o;
    }
    if (l32 == 0) sbest[2*w + half] = (int)(best & 0xffffffffu);
    __syncthreads();

    // QB*NK = 288 coefficient outputs.
    for (int t = tid; t < QB*NK; t += 256) {
        const int qq  = t / NK;
        const int k   = t - qq*NK;
        const int idx = sbest[qq];
        const int b   = blockIdx.x * QB + qq;
        float acc = 0.f;
        if (k < NP) {
            #pragma unroll
            for (int p = 0; p < NP; ++p)
                acc += poly_dic[idx*NP + p] * sap[p*NP + k];
        } else {
            const int g = k - NP;
            #pragma unroll
            for (int e = 0; e < NE; ++e)
                acc += graph_dic[idx*NE + e] * sag[e*NG + g];
        }
        coeffT[(size_t)k*NB + b] = acc;
    }
}

// ---------------------------------------------------------------------------
// Kernel 2: out[b][j] = sum_k coeffT[k][b] * S_all[k][j]
// S REGISTER-RESIDENT: each thread keeps its 2-column slice of ALL 36 S rows
// in VGPRs (72 regs), loaded once per block, then sweeps TILES=8 row tiles
// of RB=16 rows. Per tile: 36 x (16 uniform coeff s_loads + 32 FMAs/thread)
// straight-line, then 16 nontemporal dwordx2 stores. The only per-k memory
// dependency is the scalar-cache-hot coeff row; S-load L2 latency is paid
// once instead of per (tile,k). Stores of tile t overlap compute of t+1
// (no barriers) -> store pipe streams continuously.
// Register budget: 72 S + 32 acc + misc ~ 124 VGPR -> 4 waves/SIMD.
// grid = (NDD/(256*CT)=128, (NB/RB)/TILES=16).
// ---------------------------------------------------------------------------
__global__ __launch_bounds__(256) void expand_kernel(
    const float* __restrict__ coeffT,   // [NK][NB]
    const float* __restrict__ S_poly,   // [NP][NDD]
    const float* __restrict__ S_graph,  // [NG][NDD]
    float* __restrict__ out)            // [NB][NDD]
{
    const int j  = (blockIdx.x * 256 + threadIdx.x) * CT;
    const int y0 = blockIdx.y * TILES;

    // Stage this thread's 2-wide column slice of all 36 S rows in VGPRs.
    vfloat2 sreg[NK];
    #pragma unroll
    for (int k = 0; k < NP; ++k)
        sreg[k] = *(const vfloat2*)(S_poly + (size_t)k*NDD + j);
    #pragma unroll
    for (int k = 0; k < NG; ++k)
        sreg[NP + k] = *(const vfloat2*)(S_graph + (size_t)k*NDD + j);

    for (int t = 0; t < TILES; ++t) {
        const int b0 = (y0 + t) * RB;
        const float* __restrict__ cb = coeffT + b0;   // wave-uniform

        vfloat2 acc[RB];
        #pragma unroll
        for (int r = 0; r < RB; ++r) acc[r] = (vfloat2)0.f;

        #pragma unroll
        for (int k = 0; k < NK; ++k) {
            const float* cr = cb + (size_t)k * NB;    // uniform -> s_load
            vfloat4 c0 = *(const vfloat4*)(cr + 0);
            vfloat4 c1 = *(const vfloat4*)(cr + 4);
            vfloat4 c2 = *(const vfloat4*)(cr + 8);
            vfloat4 c3 = *(const vfloat4*)(cr + 12);
            const vfloat2 sv = sreg[k];
            #pragma unroll
            for (int r = 0; r < 4; ++r) acc[r     ] += c0[r] * sv;
            #pragma unroll
            for (int r = 0; r < 4; ++r) acc[r + 4 ] += c1[r] * sv;
            #pragma unroll
            for (int r = 0; r < 4; ++r) acc[r + 8 ] += c2[r] * sv;
            #pragma unroll
            for (int r = 0; r < 4; ++r) acc[r + 12] += c3[r] * sv;
        }

        #pragma unroll
        for (int r = 0; r < RB; ++r) {
            __builtin_nontemporal_store(
                acc[r], (vfloat2*)(out + (size_t)(b0 + r)*NDD + j));
        }
    }
}

extern "C" void kernel_launch(void* const* d_in, const int* in_sizes, int n_in,
                              void* d_out, int out_size, void* d_ws, size_t ws_size,
                              hipStream_t stream) {
    const float* positions   = (const float*)d_in[0];
    const float* obs_pos     = (const float*)d_in[1];
    const float* poly_dic    = (const float*)d_in[2];
    const float* graph_dic   = (const float*)d_in[3];
    const float* alpha_poly  = (const float*)d_in[4];
    const float* alpha_graph = (const float*)d_in[5];
    const float* S_poly      = (const float*)d_in[6];
    const float* S_graph     = (const float*)d_in[7];
    float* out = (float*)d_out;

    float* coeffT = (float*)d_ws;   // NK*NB floats = 288 KB (transposed)

    knn_coeff_kernel<<<NB/QB, 256, 0, stream>>>(
        positions, obs_pos, poly_dic, graph_dic, alpha_poly, alpha_graph, coeffT);

    dim3 grid2(NDD/(256*CT), (NB/RB)/TILES);
    expand_kernel<<<grid2, 256, 0, stream>>>(coeffT, S_poly, S_graph, out);
}